// Round 1
// baseline (46.903 us; speedup 1.0000x reference)
//
#include <hip/hip_runtime.h>
#include <math.h>

#define DFEAT 50
#define NS 200          // max series terms (reference uses 200)
#define BLOCK 256

// C = 25*ln(2*pi) - 24*ln(2)  (the kappa-independent constant in -log_cmk)
#define CADD 29.311394326794948f
#define LN2F 0.6931471805599453f

__global__ __launch_bounds__(BLOCK) void nllvmf_kernel(const float* __restrict__ in,
                                                       float* __restrict__ out,
                                                       int rows) {
    __shared__ float c2[NS];   // c2[j] = (lgamma(j+1)+lgamma(j+25)) * log2(e)
    __shared__ float wsum[BLOCK / 64];

    const int tid = threadIdx.x;

    // Build the row-independent coefficient table once per block.
    if (tid < NS) {
        float j = (float)tid;
        c2[tid] = (lgammaf(j + 1.0f) + lgammaf(j + 25.0f)) * 1.4426950408889634f;
    }
    __syncthreads();

    const int row = blockIdx.x * BLOCK + tid;
    float v = 0.0f;

    if (row < rows) {
        // ---- kappa = L1 norm of the row (25 x float2, 8B-aligned: 200B rows) ----
        const float2* p = (const float2*)(in + (size_t)row * DFEAT);
        float kappa = 0.0f;
#pragma unroll
        for (int i = 0; i < DFEAT / 2; ++i) {
            float2 x = p[i];
            kappa += fabsf(x.x) + fabsf(x.y);
        }

        // ---- series in log2 space: t_j = j * (2*log2(kappa/2)) - c2[j] ----
        const float lx2 = 2.0f * log2f(kappa * 0.5f);

        // pass 1: running max, wave-uniform early exit once all lanes are
        // >30 (log2) past their peak (series is concave in j -> unimodal).
        float m = -1e30f;
        int jend = NS - 1;
        for (int j = 0; j < NS; ++j) {
            float t = fmaf((float)j, lx2, -c2[j]);
            m = fmaxf(m, t);
            if (__all(t < m - 30.0f)) { jend = j; break; }
        }

        // pass 2: sum exp2(t - m) over the significant range
        float s = 0.0f;
        for (int j = 0; j <= jend; ++j) {
            float t = fmaf((float)j, lx2, -c2[j]);
            s += exp2f(t - m);
        }

        // -log_cmk = LSE_ln + C  (V*log(kappa) terms cancel to V*ln2, folded into C)
        v = fmaf(m + log2f(s), LN2F, CADD);
    }

    // ---- reduction: wave butterfly -> LDS -> one atomic per block ----
#pragma unroll
    for (int off = 32; off > 0; off >>= 1)
        v += __shfl_xor(v, off);

    const int wave = tid >> 6;
    if ((tid & 63) == 0) wsum[wave] = v;
    __syncthreads();

    if (tid == 0) {
        float b = 0.0f;
#pragma unroll
        for (int w = 0; w < BLOCK / 64; ++w) b += wsum[w];
        atomicAdd(out, b * (1.0f / 524288.0f));
    }
}

extern "C" void kernel_launch(void* const* d_in, const int* in_sizes, int n_in,
                              void* d_out, int out_size, void* d_ws, size_t ws_size,
                              hipStream_t stream) {
    const float* in = (const float*)d_in[0];   // target (d_in[1]) is unused by the reference
    float* out = (float*)d_out;
    const int rows = in_sizes[0] / DFEAT;      // 524288

    hipMemsetAsync(d_out, 0, sizeof(float), stream);

    const int grid = (rows + BLOCK - 1) / BLOCK;
    nllvmf_kernel<<<grid, BLOCK, 0, stream>>>(in, out, rows);
}